// Round 10
// baseline (244.664 us; speedup 1.0000x reference)
//
#include <hip/hip_runtime.h>
#include <hip/hip_bf16.h>
#include <stdint.h>

#define HWsz 3136
#define Hh   56
#define Cc   384
#define NHEADS 6
#define NB   8

typedef __attribute__((ext_vector_type(8))) short short8;
typedef __attribute__((ext_vector_type(4))) short short4v;
typedef __attribute__((ext_vector_type(4))) float f32x4;

static __device__ __forceinline__ short f2bf(float f) {
  __hip_bfloat16 h = __float2bfloat16(f);
  return (short)__builtin_bit_cast(unsigned short, h);
}
// async global->LDS, 16B per lane: lds gets base + lane*16, src is per-lane
static __device__ __forceinline__ void gload16(const void* g, void* l) {
  __builtin_amdgcn_global_load_lds(
      (const __attribute__((address_space(1))) void*)g,
      (__attribute__((address_space(3))) void*)l, 16, 0, 0);
}

// ---------------- weight prep: convert to bf16 into TILED layout [om][12][128][40]
// (LDS-image tiles, 8 pad shorts/row; pads never read). q rows scaled by 0.125.
__global__ void prep_weights(const float* __restrict__ wq, const float* __restrict__ wp,
                             short* __restrict__ wqt, short* __restrict__ wpt) {
  int stride = gridDim.x * blockDim.x;
  for (int i = blockIdx.x * blockDim.x + threadIdx.x; i < 3 * Cc * Cc; i += stride) {
    int o = i / Cc, k = i - o * Cc;
    float v = wq[i] * (o < Cc ? 0.125f : 1.0f);
    wqt[(((o >> 7) * 12 + (k >> 5)) * 128 + (o & 127)) * 40 + (k & 31)] = f2bf(v);
  }
  for (int i = blockIdx.x * blockDim.x + threadIdx.x; i < Cc * Cc; i += stride) {
    int o = i / Cc, k = i - o * Cc;
    wpt[(((o >> 7) * 12 + (k >> 5)) * 128 + (o & 127)) * 40 + (k & 31)] = f2bf(wp[i]);
  }
}

// ---------------- x (B,C,HW) f32 -> tiled bf16 xTt[b][pn=25][k0=12][128][40]
__global__ __launch_bounds__(256) void transpose_x(const float* __restrict__ x,
                                                   short* __restrict__ xTt) {
  __shared__ float tf[32][129];
  const int blk = blockIdx.x;
  const int b = blk & 7;
  const int idx = blk >> 3;
  const int pni = idx >> 2;
  const int kg  = idx & 3;
  const int p0 = pni * 128;
  const int t = threadIdx.x;
  const float* xb = x + (size_t)b * Cc * HWsz;
  short* outb = xTt + ((size_t)(b * 25 + pni)) * 12 * 5120;
  const int cc = t >> 3, pq = t & 7;
  const int orow = t >> 1, ohf = t & 1;
  for (int k0 = kg * 3; k0 < kg * 3 + 3; ++k0) {
    const float* crow = xb + (size_t)(k0 * 32 + cc) * HWsz;
#pragma unroll
    for (int i = 0; i < 4; ++i) {
      int p = p0 + pq * 16 + i * 4;
      if (p > HWsz - 4) p = HWsz - 4;
      f32x4 v = *(const f32x4*)(crow + p);
      tf[cc][pq * 16 + i * 4 + 0] = v[0];
      tf[cc][pq * 16 + i * 4 + 1] = v[1];
      tf[cc][pq * 16 + i * 4 + 2] = v[2];
      tf[cc][pq * 16 + i * 4 + 3] = v[3];
    }
    __syncthreads();
    short8 s0, s1;
#pragma unroll
    for (int i = 0; i < 8; ++i) s0[i] = f2bf(tf[ohf * 16 + i][orow]);
#pragma unroll
    for (int i = 0; i < 8; ++i) s1[i] = f2bf(tf[ohf * 16 + 8 + i][orow]);
    short* orp = outb + k0 * 5120 + orow * 40 + ohf * 16;
    *(short8*)(orp)     = s0;
    *(short8*)(orp + 8) = s1;
    __syncthreads();
  }
}

// ---------------- bf16 MFMA GEMM, m97-style: global_load_lds both operands.
template<int MODE>
__global__ __launch_bounds__(256) void gemm_bf16(
    const short* __restrict__ At, const short* __restrict__ Bt,
    const float* __restrict__ bias, void* __restrict__ o1, void* __restrict__ o2)
{
  constexpr int NOM = (MODE == 0 ? 9 : 3);
  const int b   = blockIdx.x & 7;
  const int idx = blockIdx.x >> 3;
  const int omi = idx % NOM;
  const int pni = idx / NOM;
  const int om0 = omi * 128, pn0 = pni * 128;
  __shared__ short lA[5120];
  __shared__ short lB[5120];
  const int t = threadIdx.x, lane = t & 63, wave = t >> 6;
  const int wm = (wave >> 1) * 64, wn = (wave & 1) * 64;
  const int fr = lane & 15, fo = lane >> 4;
  f32x4 acc[4][4] = {};
  const short* Abase = At + omi * 12 * 5120;
  const short* Bbase = Bt + ((size_t)(b * 25 + pni)) * 12 * 5120;

  for (int k0i = 0; k0i < 12; ++k0i) {
    __syncthreads();
    const short* Ats = Abase + k0i * 5120;
    const short* Bts = Bbase + k0i * 5120;
#pragma unroll
    for (int c = 0; c < 5; ++c) {
      const int g = wave * 5 + c;
      const short* src = (g < 10 ? Ats + g * 512 : Bts + (g - 10) * 512) + lane * 8;
      short* dst = (g < 10 ? lA + g * 512 : lB + (g - 10) * 512);
      gload16(src, dst);
    }
    __syncthreads();
    short8 af[4], bfr[4];
#pragma unroll
    for (int m = 0; m < 4; ++m) af[m]  = *(const short8*)(lA + (wm + m * 16 + fr) * 40 + fo * 8);
#pragma unroll
    for (int n = 0; n < 4; ++n) bfr[n] = *(const short8*)(lB + (wn + n * 16 + fr) * 40 + fo * 8);
#pragma unroll
    for (int m = 0; m < 4; ++m)
#pragma unroll
      for (int n = 0; n < 4; ++n)
        acc[m][n] = __builtin_amdgcn_mfma_f32_16x16x32_bf16(af[m], bfr[n], acc[m][n], 0, 0, 0);
  }
  if (MODE == 0) {
    if (om0 < 768) {
      short* outq = (short*)o1 + (size_t)b * HWsz * 768;
#pragma unroll
      for (int m = 0; m < 4; ++m) {
        int ob = om0 + wm + m * 16 + (lane >> 4) * 4;
        float bs[4];
#pragma unroll
        for (int r = 0; r < 4; ++r) { int o = ob + r; bs[r] = bias[o] * (o < Cc ? 0.125f : 1.0f); }
#pragma unroll
        for (int n = 0; n < 4; ++n) {
          int p = pn0 + wn + n * 16 + fr;
          if (p < HWsz) {
            short4v s;
#pragma unroll
            for (int r = 0; r < 4; ++r) s[r] = f2bf(acc[m][n][r] + bs[r]);
            *(short4v*)(outq + (size_t)p * 768 + ob) = s;
          }
        }
      }
    } else {
      short* vtp = (short*)o2;
#pragma unroll
      for (int m = 0; m < 4; ++m) {
        int ob = om0 + wm + m * 16 + (lane >> 4) * 4;
#pragma unroll
        for (int n = 0; n < 4; ++n) {
          int p = pn0 + wn + n * 16 + fr;
          if (p < HWsz) {
            int ii = p / Hh, jj = p % Hh;
#pragma unroll
            for (int r = 0; r < 4; ++r) {
              int ch = ob + r - 768;
              vtp[((b * Cc + ch) * 62 + ii + 3) * 64 + jj + 3] = f2bf(acc[m][n][r] + bias[ob + r]);
            }
          }
        }
      }
    }
  } else {
    float* outo = (float*)o1 + (size_t)b * Cc * HWsz;
#pragma unroll
    for (int m = 0; m < 4; ++m) {
      int ob = om0 + wm + m * 16 + (lane >> 4) * 4;
#pragma unroll
      for (int n = 0; n < 4; ++n) {
        int p = pn0 + wn + n * 16 + fr;
        if (p < HWsz) {
#pragma unroll
          for (int r = 0; r < 4; ++r)
            outo[(size_t)(ob + r) * HWsz + p] = acc[m][n][r] + bias[ob + r];
        }
      }
    }
  }
}

// ---------------- MFMA neighborhood attention, software-pipelined.
// grid 8*147: b = blk&7 (XCD pin); rr = blk>>3; 2 tiles/block (294 = 2*147 exact).
// Per tile: 7-chunk kc loop with NEXT-chunk K-frag register prefetch (chain head
// hidden under QK+softmax+PV); V issued at iter top; setprio(1) around MFMA.
__global__ __launch_bounds__(256, 5) void attn_mfma(
    const short* __restrict__ qkv,  // [b][3136][768] (q|k)
    const short* __restrict__ vtp,  // [b][384][62][64]
    short* __restrict__ aoutT)      // [b][25][12][128][40]
{
  __shared__ short P[64 * 40];
  const int blk = blockIdx.x;
  const int b = blk & 7;
  const int rr = blk >> 3;
  const int t = threadIdx.x, lane = t & 63, w = t >> 6;
  const int fr = lane & 15, fo = lane >> 4;
  const int qkvb = b * HWsz * 768;
  const short8 z = (short8)0;
  short* ab = aoutT + (size_t)b * 25 * 12 * 5120;

#pragma unroll 1
  for (int ti = 0; ti < 2; ++ti) {
    const int tau = rr * 2 + ti;
    const int h = tau / 49, tile = tau % 49;
    const int i0 = (tile / 7) * 8, j0 = (tile % 7) * 8;

    const int q_idx = w * 16 + fr;
    const int qr = q_idx >> 3, qc = q_idx & 7;
    const short* qp = qkv + qkvb + ((i0 + qr) * Hh + j0 + qc) * 768 + h * 64 + fo * 8;
    short8 qf0 = *(const short8*)(qp);
    short8 qf1 = *(const short8*)(qp + 32);

    const int kj = j0 + fr - 3;
    const bool jok = (unsigned)kj < (unsigned)Hh;
    const int kjs = kj < 0 ? 0 : (kj > Hh - 1 ? Hh - 1 : kj);
    const short* kcol = qkv + qkvb + Cc + h * 64 + fo * 8;

    f32x4 oacc[4] = {};
    float sum = 0.f;

    // prologue: K-frags for chunk 0
    short8 kf00, kf01, kf10, kf11;
    {
      int ki0 = i0 - 3;      int kis0 = ki0 < 0 ? 0 : (ki0 > Hh - 1 ? Hh - 1 : ki0);
      int ki1 = i0 - 2;      int kis1 = ki1 < 0 ? 0 : (ki1 > Hh - 1 ? Hh - 1 : ki1);
      const short8* ka = (const short8*)(kcol + (kis0 * Hh + kjs) * 768);
      const short8* kb = (const short8*)(kcol + (kis1 * Hh + kjs) * 768);
      kf00 = ka[0]; kf01 = ka[4]; kf10 = kb[0]; kf11 = kb[4];
    }

#pragma unroll
    for (int kc = 0; kc < 7; ++kc) {
      // V loads for this chunk (issued early; used after softmax)
      short8 vf[4];
      const int vrow = i0 + 2 * kc + (fo >> 1);
      const int vcol = j0 + (fo & 1) * 8;
#pragma unroll
      for (int n = 0; n < 4; ++n)
        vf[n] = *(const short8*)(vtp + ((b * Cc + h * 64 + 16 * n + fr) * 62 + vrow) * 64 + vcol);
      // prefetch next chunk's K-frags (pure loads, masked at use)
      short8 nf00 = z, nf01 = z, nf10 = z, nf11 = z;
      if (kc < 6) {
        int ki0 = i0 + 2 * kc - 1;  int kis0 = ki0 < 0 ? 0 : (ki0 > Hh - 1 ? Hh - 1 : ki0);
        int ki1 = i0 + 2 * kc;      int kis1 = ki1 < 0 ? 0 : (ki1 > Hh - 1 ? Hh - 1 : ki1);
        const short8* ka = (const short8*)(kcol + (kis0 * Hh + kjs) * 768);
        const short8* kb = (const short8*)(kcol + (kis1 * Hh + kjs) * 768);
        nf00 = ka[0]; nf01 = ka[4]; nf10 = kb[0]; nf11 = kb[4];
      }
      const bool ok0 = jok && ((unsigned)(i0 + 2 * kc - 3) < (unsigned)Hh);
      const bool ok1 = jok && ((unsigned)(i0 + 2 * kc - 2) < (unsigned)Hh);
      short8 a00 = ok0 ? kf00 : z, a01 = ok0 ? kf01 : z;
      short8 a10 = ok1 ? kf10 : z, a11 = ok1 ? kf11 : z;
      f32x4 s0 = {}, s1 = {};
      __builtin_amdgcn_s_setprio(1);
      s0 = __builtin_amdgcn_mfma_f32_16x16x32_bf16(a00, qf0, s0, 0, 0, 0);
      s0 = __builtin_amdgcn_mfma_f32_16x16x32_bf16(a01, qf1, s0, 0, 0, 0);
      s1 = __builtin_amdgcn_mfma_f32_16x16x32_bf16(a10, qf0, s1, 0, 0, 0);
      s1 = __builtin_amdgcn_mfma_f32_16x16x32_bf16(a11, qf1, s1, 0, 0, 0);
      __builtin_amdgcn_s_setprio(0);
#pragma unroll
      for (int mloc = 0; mloc < 2; ++mloc) {
        const f32x4 sv = mloc ? s1 : s0;
        int dpr = 2 * kc + mloc - qr;
        bool rok = (unsigned)dpr <= 6u;
        short4v pk;
#pragma unroll
        for (int r = 0; r < 4; ++r) {
          int dpc = fo * 4 + r - qc;
          float e = (rok && (unsigned)dpc <= 6u) ? __expf(sv[r]) : 0.f;
          sum += e;
          pk[r] = f2bf(e);
        }
        *(short4v*)(P + q_idx * 40 + mloc * 16 + fo * 4) = pk;
      }
      short8 pa = *(const short8*)(P + q_idx * 40 + fo * 8);
      __builtin_amdgcn_s_setprio(1);
#pragma unroll
      for (int n = 0; n < 4; ++n)
        oacc[n] = __builtin_amdgcn_mfma_f32_16x16x32_bf16(pa, vf[n], oacc[n], 0, 0, 0);
      __builtin_amdgcn_s_setprio(0);
      if (kc < 6) { kf00 = nf00; kf01 = nf01; kf10 = nf10; kf11 = nf11; }
    }

    sum += __shfl_xor(sum, 16);
    sum += __shfl_xor(sum, 32);
    float inv[4];
#pragma unroll
    for (int r = 0; r < 4; ++r) inv[r] = 1.0f / __shfl(sum, fo * 4 + r);
    const int owr = i0 + 2 * w + (fo >> 1);
    const int owc = j0 + (fo & 1) * 4;
#pragma unroll
    for (int n = 0; n < 4; ++n) {
      const int k0 = 2 * h + (n >> 1);
      const int kk = 16 * (n & 1) + fr;
#pragma unroll
      for (int r = 0; r < 4; ++r) {
        int p = owr * Hh + owc + r;
        ab[((size_t)((p >> 7) * 12 + k0)) * 5120 + (p & 127) * 40 + kk] = f2bf(oacc[n][r] * inv[r]);
      }
    }
  }
}

extern "C" void kernel_launch(void* const* d_in, const int* in_sizes, int n_in,
                              void* d_out, int out_size, void* d_ws, size_t ws_size,
                              hipStream_t stream) {
  const float* x      = (const float*)d_in[0];
  const float* w_qkv  = (const float*)d_in[1];
  const float* b_qkv  = (const float*)d_in[2];
  const float* w_proj = (const float*)d_in[3];
  const float* b_proj = (const float*)d_in[4];

  char* ws = (char*)d_ws;
  // qk 38,535,168 | vtp 24,379,392 | xTt/aoutT 24,576,000 | wqt 1,105,920 | wpt 368,640
  short* qk  = (short*)ws;
  short* vtp = (short*)(ws + 38535168);
  short* xTt = (short*)(ws + 38535168 + 24379392);
  short* wqt = (short*)(ws + 38535168 + 24379392 + 24576000);
  short* wpt = (short*)(ws + 38535168 + 24379392 + 24576000 + 1105920);

  prep_weights<<<512, 256, 0, stream>>>(w_qkv, w_proj, wqt, wpt);
  hipMemsetAsync(vtp, 0, 24379392, stream);     // zero-pad borders for V image
  transpose_x<<<8 * 100, 256, 0, stream>>>(x, xTt);
  gemm_bf16<0><<<8 * 225, 256, 0, stream>>>(wqt, xTt, b_qkv, qk, vtp);
  attn_mfma<<<8 * 147, 256, 0, stream>>>(qk, vtp, xTt);   // xTt reused as aoutT
  gemm_bf16<1><<<8 * 75, 256, 0, stream>>>(wpt, xTt, b_proj, d_out, nullptr);
}

// Round 11
// 207.650 us; speedup vs baseline: 1.1782x; 1.1782x over previous
//
#include <hip/hip_runtime.h>
#include <hip/hip_bf16.h>
#include <stdint.h>

#define HWsz 3136
#define Hh   56
#define Cc   384
#define NHEADS 6
#define NB   8

typedef __attribute__((ext_vector_type(8))) short short8;
typedef __attribute__((ext_vector_type(4))) short short4v;
typedef __attribute__((ext_vector_type(4))) float f32x4;

static __device__ __forceinline__ short f2bf(float f) {
  __hip_bfloat16 h = __float2bfloat16(f);
  return (short)__builtin_bit_cast(unsigned short, h);
}
// async global->LDS, 16B per lane: lds gets base + lane*16, src is per-lane
static __device__ __forceinline__ void gload16(const void* g, void* l) {
  __builtin_amdgcn_global_load_lds(
      (const __attribute__((address_space(1))) void*)g,
      (__attribute__((address_space(3))) void*)l, 16, 0, 0);
}

// ---------------- weight prep: convert to bf16 into TILED layout [om][12][128][40]
__global__ void prep_weights(const float* __restrict__ wq, const float* __restrict__ wp,
                             short* __restrict__ wqt, short* __restrict__ wpt) {
  int stride = gridDim.x * blockDim.x;
  for (int i = blockIdx.x * blockDim.x + threadIdx.x; i < 3 * Cc * Cc; i += stride) {
    int o = i / Cc, k = i - o * Cc;
    float v = wq[i] * (o < Cc ? 0.125f : 1.0f);
    wqt[(((o >> 7) * 12 + (k >> 5)) * 128 + (o & 127)) * 40 + (k & 31)] = f2bf(v);
  }
  for (int i = blockIdx.x * blockDim.x + threadIdx.x; i < Cc * Cc; i += stride) {
    int o = i / Cc, k = i - o * Cc;
    wpt[(((o >> 7) * 12 + (k >> 5)) * 128 + (o & 127)) * 40 + (k & 31)] = f2bf(wp[i]);
  }
}

// ---------------- x (B,C,HW) f32 -> tiled bf16 xTt[b][pn=25][k0=12][128][40]
__global__ __launch_bounds__(256) void transpose_x(const float* __restrict__ x,
                                                   short* __restrict__ xTt) {
  __shared__ float tf[32][129];
  const int blk = blockIdx.x;
  const int b = blk & 7;
  const int idx = blk >> 3;
  const int pni = idx >> 2;
  const int kg  = idx & 3;
  const int p0 = pni * 128;
  const int t = threadIdx.x;
  const float* xb = x + (size_t)b * Cc * HWsz;
  short* outb = xTt + ((size_t)(b * 25 + pni)) * 12 * 5120;
  const int cc = t >> 3, pq = t & 7;
  const int orow = t >> 1, ohf = t & 1;
  for (int k0 = kg * 3; k0 < kg * 3 + 3; ++k0) {
    const float* crow = xb + (size_t)(k0 * 32 + cc) * HWsz;
#pragma unroll
    for (int i = 0; i < 4; ++i) {
      int p = p0 + pq * 16 + i * 4;
      if (p > HWsz - 4) p = HWsz - 4;
      f32x4 v = *(const f32x4*)(crow + p);
      tf[cc][pq * 16 + i * 4 + 0] = v[0];
      tf[cc][pq * 16 + i * 4 + 1] = v[1];
      tf[cc][pq * 16 + i * 4 + 2] = v[2];
      tf[cc][pq * 16 + i * 4 + 3] = v[3];
    }
    __syncthreads();
    short8 s0, s1;
#pragma unroll
    for (int i = 0; i < 8; ++i) s0[i] = f2bf(tf[ohf * 16 + i][orow]);
#pragma unroll
    for (int i = 0; i < 8; ++i) s1[i] = f2bf(tf[ohf * 16 + 8 + i][orow]);
    short* orp = outb + k0 * 5120 + orow * 40 + ohf * 16;
    *(short8*)(orp)     = s0;
    *(short8*)(orp + 8) = s1;
    __syncthreads();
  }
}

// ---------------- bf16 MFMA GEMM, m97-style: global_load_lds both operands.
// MODE 0 epilogue: omi<3 -> qbuf[b][p][384]; omi 3..5 -> kimg[b][62][64][384]
//                  (zero-padded image); omi 6..8 -> vtp[b][384][62][64].
// MODE 1: out f32 [b][o][3136]
template<int MODE>
__global__ __launch_bounds__(256) void gemm_bf16(
    const short* __restrict__ At, const short* __restrict__ Bt,
    const float* __restrict__ bias, void* __restrict__ o1, void* __restrict__ o2,
    void* __restrict__ o3)
{
  constexpr int NOM = (MODE == 0 ? 9 : 3);
  const int b   = blockIdx.x & 7;
  const int idx = blockIdx.x >> 3;
  const int omi = idx % NOM;
  const int pni = idx / NOM;
  const int om0 = omi * 128, pn0 = pni * 128;
  __shared__ short lA[5120];
  __shared__ short lB[5120];
  const int t = threadIdx.x, lane = t & 63, wave = t >> 6;
  const int wm = (wave >> 1) * 64, wn = (wave & 1) * 64;
  const int fr = lane & 15, fo = lane >> 4;
  f32x4 acc[4][4] = {};
  const short* Abase = At + omi * 12 * 5120;
  const short* Bbase = Bt + ((size_t)(b * 25 + pni)) * 12 * 5120;

  for (int k0i = 0; k0i < 12; ++k0i) {
    __syncthreads();
    const short* Ats = Abase + k0i * 5120;
    const short* Bts = Bbase + k0i * 5120;
#pragma unroll
    for (int c = 0; c < 5; ++c) {
      const int g = wave * 5 + c;
      const short* src = (g < 10 ? Ats + g * 512 : Bts + (g - 10) * 512) + lane * 8;
      short* dst = (g < 10 ? lA + g * 512 : lB + (g - 10) * 512);
      gload16(src, dst);
    }
    __syncthreads();
    short8 af[4], bfr[4];
#pragma unroll
    for (int m = 0; m < 4; ++m) af[m]  = *(const short8*)(lA + (wm + m * 16 + fr) * 40 + fo * 8);
#pragma unroll
    for (int n = 0; n < 4; ++n) bfr[n] = *(const short8*)(lB + (wn + n * 16 + fr) * 40 + fo * 8);
#pragma unroll
    for (int m = 0; m < 4; ++m)
#pragma unroll
      for (int n = 0; n < 4; ++n)
        acc[m][n] = __builtin_amdgcn_mfma_f32_16x16x32_bf16(af[m], bfr[n], acc[m][n], 0, 0, 0);
  }
  if (MODE == 0) {
    if (om0 < 384) {          // Q -> qbuf[b][p][384], scaled bias
      short* outq = (short*)o1 + (size_t)b * HWsz * 384;
#pragma unroll
      for (int m = 0; m < 4; ++m) {
        int ob = om0 + wm + m * 16 + (lane >> 4) * 4;
        float bs[4];
#pragma unroll
        for (int r = 0; r < 4; ++r) bs[r] = bias[ob + r] * 0.125f;
#pragma unroll
        for (int n = 0; n < 4; ++n) {
          int p = pn0 + wn + n * 16 + fr;
          if (p < HWsz) {
            short4v s;
#pragma unroll
            for (int r = 0; r < 4; ++r) s[r] = f2bf(acc[m][n][r] + bs[r]);
            *(short4v*)(outq + (size_t)p * 384 + ob) = s;
          }
        }
      }
    } else if (om0 < 768) {   // K -> kimg[b][62][64][384] (borders pre-zeroed)
      short* kimg = (short*)o2;
#pragma unroll
      for (int m = 0; m < 4; ++m) {
        int ob = om0 + wm + m * 16 + (lane >> 4) * 4;
#pragma unroll
        for (int n = 0; n < 4; ++n) {
          int p = pn0 + wn + n * 16 + fr;
          if (p < HWsz) {
            int ii = p / Hh, jj = p % Hh;
            short4v s;
#pragma unroll
            for (int r = 0; r < 4; ++r) s[r] = f2bf(acc[m][n][r] + bias[ob + r]);
            *(short4v*)(kimg + ((size_t)(b * 62 + ii + 3) * 64 + jj + 3) * 384 + ob - 384) = s;
          }
        }
      }
    } else {                  // V -> vtp[b][384][62][64] (borders pre-zeroed)
      short* vtp = (short*)o3;
#pragma unroll
      for (int m = 0; m < 4; ++m) {
        int ob = om0 + wm + m * 16 + (lane >> 4) * 4;
#pragma unroll
        for (int n = 0; n < 4; ++n) {
          int p = pn0 + wn + n * 16 + fr;
          if (p < HWsz) {
            int ii = p / Hh, jj = p % Hh;
#pragma unroll
            for (int r = 0; r < 4; ++r) {
              int ch = ob + r - 768;
              vtp[((b * Cc + ch) * 62 + ii + 3) * 64 + jj + 3] = f2bf(acc[m][n][r] + bias[ob + r]);
            }
          }
        }
      }
    }
  } else {
    float* outo = (float*)o1 + (size_t)b * Cc * HWsz;
#pragma unroll
    for (int m = 0; m < 4; ++m) {
      int ob = om0 + wm + m * 16 + (lane >> 4) * 4;
#pragma unroll
      for (int n = 0; n < 4; ++n) {
        int p = pn0 + wn + n * 16 + fr;
        if (p < HWsz) {
#pragma unroll
          for (int r = 0; r < 4; ++r)
            outo[(size_t)(ob + r) * HWsz + p] = acc[m][n][r] + bias[ob + r];
        }
      }
    }
  }
}

// ---------------- MFMA neighborhood attention, LDS-staged K/V patch.
// grid 8*294: b = blk&7 (XCD pin), h-major tile order (R9).
// Stage: K patch 224pos x 128B (coalesced 128B segments, 16B-chunk XOR swizzle);
//        V patch [64ch][232] (pos-contiguous rows). Then 7 chunks, zero global loads.
// Image zero-padding (kimg/vtp borders) replaces all K/V boundary masking.
__global__ __launch_bounds__(256) void attn_mfma(
    const short* __restrict__ qbuf, // [b][3136][384]
    const short* __restrict__ kimg, // [b][62][64][384]
    const short* __restrict__ vtp,  // [b][384][62][64]
    short* __restrict__ aoutT)      // [b][25][12][128][40]
{
  __shared__ short Kl[224 * 64];    // [pos][64ch], 16B chunk c stored at c^(pos&7)
  __shared__ short Vl[64 * 232];    // [ch][224+8 pad]
  __shared__ short P[64 * 40];
  const int blk = blockIdx.x;
  const int b = blk & 7;
  const int r_ = blk >> 3;
  const int h = r_ / 49;
  const int tile = r_ % 49;
  const int i0 = (tile / 7) * 8, j0 = (tile % 7) * 8;
  const int t = threadIdx.x, lane = t & 63, w = t >> 6;
  const int fr = lane & 15, fo = lane >> 4;

  // ---- stage K: 224 pos x 8 chunks = 1792 tasks = 7 x 256
  {
    const short* kb = kimg + ((size_t)(b * 62 + i0) * 64 + j0) * 384 + h * 64;
#pragma unroll
    for (int it = 0; it < 7; ++it) {
      int tau = it * 256 + t;
      int pos = tau >> 3, c = tau & 7;
      int prow = pos >> 4, pcol = pos & 15;
      short8 v = *(const short8*)(kb + ((size_t)prow * 64 + pcol) * 384 + c * 8);
      *(short8*)(Kl + pos * 64 + ((c ^ (pos & 7)) * 8)) = v;
    }
    // ---- stage V: 64ch x 14 rows x 2 halves = 1792 tasks
    const short* vb = vtp + ((size_t)(b * Cc + h * 64) * 62 + i0) * 64 + j0;
#pragma unroll
    for (int it = 0; it < 7; ++it) {
      int tau = it * 256 + t;
      int ch = tau / 28, rp = tau - ch * 28;
      int row = rp >> 1, half = rp & 1;
      short8 v = *(const short8*)(vb + ((size_t)ch * 62 + row) * 64 + half * 8);
      *(short8*)(Vl + ch * 232 + row * 16 + half * 8) = v;
    }
  }

  // Q fragments (global, once per tile)
  const int q_idx = w * 16 + fr;
  const int qr = q_idx >> 3, qc = q_idx & 7;
  const short* qp = qbuf + ((size_t)(b * HWsz) + (i0 + qr) * Hh + j0 + qc) * 384 + h * 64 + fo * 8;
  short8 qf0 = *(const short8*)(qp);
  short8 qf1 = *(const short8*)(qp + 32);

  __syncthreads();

  f32x4 oacc[4] = {};
  float sum = 0.f;

#pragma unroll
  for (int kc = 0; kc < 7; ++kc) {
    const int pos0 = 32 * kc + fr, pos1 = pos0 + 16;
    short8 a00 = *(const short8*)(Kl + pos0 * 64 + ((fo       ^ (pos0 & 7)) * 8));
    short8 a01 = *(const short8*)(Kl + pos0 * 64 + (((4 + fo) ^ (pos0 & 7)) * 8));
    short8 a10 = *(const short8*)(Kl + pos1 * 64 + ((fo       ^ (pos1 & 7)) * 8));
    short8 a11 = *(const short8*)(Kl + pos1 * 64 + (((4 + fo) ^ (pos1 & 7)) * 8));
    f32x4 s0 = {}, s1 = {};
    s0 = __builtin_amdgcn_mfma_f32_16x16x32_bf16(a00, qf0, s0, 0, 0, 0);
    s0 = __builtin_amdgcn_mfma_f32_16x16x32_bf16(a01, qf1, s0, 0, 0, 0);
    s1 = __builtin_amdgcn_mfma_f32_16x16x32_bf16(a10, qf0, s1, 0, 0, 0);
    s1 = __builtin_amdgcn_mfma_f32_16x16x32_bf16(a11, qf1, s1, 0, 0, 0);
#pragma unroll
    for (int mloc = 0; mloc < 2; ++mloc) {
      const f32x4 sv = mloc ? s1 : s0;
      int dpr = 2 * kc + mloc - qr;
      bool rok = (unsigned)dpr <= 6u;
      short4v pk;
#pragma unroll
      for (int r = 0; r < 4; ++r) {
        int dpc = fo * 4 + r - qc;
        float e = (rok && (unsigned)dpc <= 6u) ? __expf(sv[r]) : 0.f;
        sum += e;
        pk[r] = f2bf(e);
      }
      *(short4v*)(P + q_idx * 40 + mloc * 16 + fo * 4) = pk;
    }
    short8 pa = *(const short8*)(P + q_idx * 40 + fo * 8);
#pragma unroll
    for (int n = 0; n < 4; ++n) {
      short8 vf = *(const short8*)(Vl + (n * 16 + fr) * 232 + kc * 32 + fo * 8);
      oacc[n] = __builtin_amdgcn_mfma_f32_16x16x32_bf16(pa, vf, oacc[n], 0, 0, 0);
    }
  }

  sum += __shfl_xor(sum, 16);
  sum += __shfl_xor(sum, 32);
  float inv[4];
#pragma unroll
  for (int r = 0; r < 4; ++r) inv[r] = 1.0f / __shfl(sum, fo * 4 + r);
  const int owr = i0 + 2 * w + (fo >> 1);
  const int owc = j0 + (fo & 1) * 4;
  short* ab = aoutT + (size_t)b * 25 * 12 * 5120;
#pragma unroll
  for (int n = 0; n < 4; ++n) {
    const int k0 = 2 * h + (n >> 1);
    const int kk = 16 * (n & 1) + fr;
#pragma unroll
    for (int r = 0; r < 4; ++r) {
      int p = owr * Hh + owc + r;
      ab[((size_t)((p >> 7) * 12 + k0)) * 5120 + (p & 127) * 40 + kk] = f2bf(oacc[n][r] * inv[r]);
    }
  }
}

extern "C" void kernel_launch(void* const* d_in, const int* in_sizes, int n_in,
                              void* d_out, int out_size, void* d_ws, size_t ws_size,
                              hipStream_t stream) {
  const float* x      = (const float*)d_in[0];
  const float* w_qkv  = (const float*)d_in[1];
  const float* b_qkv  = (const float*)d_in[2];
  const float* w_proj = (const float*)d_in[3];
  const float* b_proj = (const float*)d_in[4];

  char* ws = (char*)d_ws;
  // qbuf 19,267,584 | kimg 24,379,392 | vtp 24,379,392 | xTt/aoutT 24,576,000
  // | wqt 1,105,920 | wpt 368,640   = 94,076,928 B
  short* qbuf = (short*)ws;
  short* kimg = (short*)(ws + 19267584);
  short* vtp  = (short*)(ws + 19267584 + 24379392);
  short* xTt  = (short*)(ws + 19267584 + 24379392 + 24379392);
  short* wqt  = (short*)(ws + 19267584 + 24379392 + 24379392 + 24576000);
  short* wpt  = (short*)(ws + 19267584 + 24379392 + 24379392 + 24576000 + 1105920);

  prep_weights<<<512, 256, 0, stream>>>(w_qkv, w_proj, wqt, wpt);
  hipMemsetAsync(kimg, 0, 24379392u + 24379392u, stream);  // zero-pad K & V image borders
  transpose_x<<<8 * 100, 256, 0, stream>>>(x, xTt);
  gemm_bf16<0><<<8 * 225, 256, 0, stream>>>(wqt, xTt, b_qkv, qbuf, kimg, vtp);
  attn_mfma<<<8 * 294, 256, 0, stream>>>(qbuf, kimg, vtp, xTt);   // xTt reused as aoutT
  gemm_bf16<1><<<8 * 75, 256, 0, stream>>>(wpt, xTt, b_proj, d_out, nullptr, nullptr);
}